// Round 6
// baseline (12.892 us; speedup 1.0000x reference)
//
#include <hip/hip_runtime.h>
#include <math.h>

#define NG     512
#define IMG_W  256
#define IMG_H  256
#define FXc    300.0f
#define FYc    300.0f
#define CXc    128.0f
#define CYc    128.0f
#define NEARc  0.01f
#define FARc   100.0f
#define MAXR   64.0f

__device__ __forceinline__ unsigned int ordered_float(float f) {
  unsigned int u = __float_as_uint(f);
  return (u & 0x80000000u) ? ~u : (u | 0x80000000u);
}

// LDS layout: 3 float4 arrays per gaussian (48 B):
//   A = {mx, my, ia, ibc}
//   B = {idv, opac, cr, cg}
//   C = {cb, bboxX(u16x0|x1<<16), bboxY(u16y0|y1<<16), depth}
__global__ __launch_bounds__(1024, 4) void fused_render_kernel(
    const float* __restrict__ pos, const float* __restrict__ scl,
    const float* __restrict__ rot, const float* __restrict__ col,
    const float* __restrict__ opa, const float* __restrict__ vm,
    float* __restrict__ out)
{
  __shared__ float4 sgA[NG];              // 8 KB
  __shared__ float4 sgB[NG];              // 8 KB
  __shared__ float4 sgC[NG];              // 8 KB
  __shared__ unsigned long long keys[NG]; // 4 KB
  __shared__ short order[NG];             // 1 KB
  __shared__ int wave_cnt[8];

  const int t = threadIdx.x;
  const int wid = t >> 6;      // 16 waves
  const int lane = t & 63;

  const int tileX = blockIdx.x & 15;
  const int tileY = blockIdx.x >> 4;
  const int tx0i = tileX * 16, ty0i = tileY * 16;

  float V[12];
#pragma unroll
  for (int k = 0; k < 12; ++k) V[k] = vm[k];

  // ---- prep: 1 gaussian per thread (t < 512); bbox/depth stay in regs ----
  int x0i = 1023, x1i = 0, y0i = 1023, y1i = 0;  // empty sentinel
  float depth = 0.f;
  if (t < NG) {
    const int i = t;

    const float p0 = pos[i*3+0], p1 = pos[i*3+1], p2 = pos[i*3+2];
    const float pcx = V[0]*p0 + V[1]*p1 + V[2]*p2  + V[3];
    const float pcy = V[4]*p0 + V[5]*p1 + V[6]*p2  + V[7];
    const float pcz = V[8]*p0 + V[9]*p1 + V[10]*p2 + V[11];
    depth = -pcz;

    float qw = rot[i*4+0], qx = rot[i*4+1], qy = rot[i*4+2], qz = rot[i*4+3];
    const float qinv = 1.f / sqrtf(qw*qw + qx*qx + qy*qy + qz*qz);
    qw *= qinv; qx *= qinv; qy *= qinv; qz *= qinv;
    const float r00 = 1.f - 2.f*(qy*qy + qz*qz);
    const float r01 = 2.f*(qx*qy - qw*qz);
    const float r02 = 2.f*(qx*qz + qw*qy);
    const float r10 = 2.f*(qx*qy + qw*qz);
    const float r11 = 1.f - 2.f*(qx*qx + qz*qz);
    const float r12 = 2.f*(qy*qz - qw*qx);
    const float r20 = 2.f*(qx*qz - qw*qy);
    const float r21 = 2.f*(qy*qz + qw*qx);
    const float r22 = 1.f - 2.f*(qx*qx + qy*qy);

    const float s0 = scl[i*3+0], s1 = scl[i*3+1], s2 = scl[i*3+2];

    const float m00 = V[0]*r00 + V[1]*r10 + V[2]*r20;
    const float m01 = V[0]*r01 + V[1]*r11 + V[2]*r21;
    const float m02 = V[0]*r02 + V[1]*r12 + V[2]*r22;
    const float m10 = V[4]*r00 + V[5]*r10 + V[6]*r20;
    const float m11 = V[4]*r01 + V[5]*r11 + V[6]*r21;
    const float m12 = V[4]*r02 + V[5]*r12 + V[6]*r22;
    const float m20 = V[8]*r00 + V[9]*r10 + V[10]*r20;
    const float m21 = V[8]*r01 + V[9]*r11 + V[10]*r21;
    const float m22 = V[8]*r02 + V[9]*r12 + V[10]*r22;

    const float a0 = m00*s0, a1 = m01*s1, a2 = m02*s2;
    const float b0 = m10*s0, b1 = m11*s1, b2 = m12*s2;
    const float c0 = m20*s0, c1 = m21*s1, c2 = m22*s2;
    const float c00 = a0*a0 + a1*a1 + a2*a2;
    const float c01 = a0*b0 + a1*b1 + a2*b2;
    const float c02 = a0*c0 + a1*c1 + a2*c2;
    const float c11 = b0*b0 + b1*b1 + b2*b2;
    const float c12 = b0*c0 + b1*c1 + b2*c2;
    const float c22 = c0*c0 + c1*c1 + c2*c2;

    const float zp = pcz + 1e-8f;
    const float sgn = (zp > 0.f) ? 1.f : ((zp < 0.f) ? -1.f : 0.f);
    const float z_safe = fmaxf(fabsf(pcz), 0.01f) * sgn;
    const float rz2 = 1.f / (z_safe * z_safe);
    const float rnz = 1.f / (-z_safe);

    const float j00 = FXc * rnz;
    const float j02 = FXc * pcx * rz2;
    const float j11 = FYc * (-rnz);
    const float j12 = FYc * pcy * rz2;

    const float t00 = j00*c00 + j02*c02;
    const float t01 = j00*c01 + j02*c12;
    const float t02 = j00*c02 + j02*c22;
    const float t10 = j11*c01 + j12*c02;
    const float t11 = j11*c11 + j12*c12;
    const float t12 = j11*c12 + j12*c22;
    const float ca  = t00*j00 + t02*j02;
    const float cbv = t01*j11 + t02*j12;
    const float cc  = t10*j00 + t12*j02;
    const float cd  = t11*j11 + t12*j12;

    const float u = FXc * pcx * rnz + CXc;
    const float v = FYc * (-pcy) * rnz + CYc;

    const float trace = ca + cd;
    const float det = fmaxf(ca*cd - cbv*cc, 1e-6f);
    const float disc = fmaxf(trace*trace - 4.f*det, 0.f);
    const float lam = (trace + sqrtf(disc)) * 0.5f;
    const float radii = fminf(3.f * sqrtf(fmaxf(lam, 1e-6f)), MAXR);

    const bool visible = (depth > NEARc) && (depth < FARc) &&
                         (u + radii > 0.f) && (u - radii < (float)IMG_W) &&
                         (v + radii > 0.f) && (v - radii < (float)IMG_H);

    const float ra = ca + 1e-4f;
    const float rb = cbv;
    const float rc = cc;
    const float rd = cd + 1e-4f;
    const float inv_rdet = 1.f / (ra*rd - rb*rc);

    if (visible) {
      x0i = (int)fmaxf(0.f, truncf(u - radii));
      x1i = (int)fminf((float)IMG_W, truncf(u + radii) + 1.f);
      y0i = (int)fmaxf(0.f, truncf(v - radii));
      y1i = (int)fminf((float)IMG_H, truncf(v + radii) + 1.f);
    }
    const unsigned int bx = (unsigned int)x0i | ((unsigned int)x1i << 16);
    const unsigned int by = (unsigned int)y0i | ((unsigned int)y1i << 16);

    sgA[i] = make_float4(u, v, rd * inv_rdet, -(rb + rc) * inv_rdet);
    sgB[i] = make_float4(ra * inv_rdet, opa[i], col[i*3+0], col[i*3+1]);
    sgC[i] = make_float4(col[i*3+2], __uint_as_float(bx), __uint_as_float(by),
                         depth);
  }

  // ---- compaction from registers (no barrier needed before ballot) ----
  bool pred = false;
  unsigned long long mb = 0;
  if (wid < 8) {
    pred = (x0i < tx0i + 16) & (x1i > tx0i) &
           (y0i < ty0i + 16) & (y1i > ty0i);
    mb = __ballot(pred);
    if (lane == 0) wave_cnt[wid] = __popcll(mb);
  }
  __syncthreads();   // wave_cnt + sg* visible

  int off = 0, total = 0;
#pragma unroll
  for (int w = 0; w < 8; ++w) {
    const int c = wave_cnt[w];
    if (w < wid) off += c;
    total += c;
  }
  if (pred) {
    const int p = off + __popcll(mb & ((1ull << lane) - 1ull));
    keys[p] = ((unsigned long long)ordered_float(depth) << 32)
            | (unsigned int)t;
  }
  __syncthreads();

  // ---- rank sort: unique keys, one key per thread, 1 barrier ----
  if (t < total) {
    const unsigned long long kj = keys[t];
    int rank = 0;
    int i = 0;
    for (; i + 4 <= total; i += 4) {
      rank += (keys[i]   < kj);
      rank += (keys[i+1] < kj);
      rank += (keys[i+2] < kj);
      rank += (keys[i+3] < kj);
    }
    for (; i < total; ++i) rank += (keys[i] < kj);
    order[rank] = (short)(kj & 0xFFFFull);
  }
  __syncthreads();

  // ---- segmented composite: 4 threads/pixel, contiguous quarters ----
  const int p = t >> 2;        // pixel 0..255
  const int seg = t & 3;       // segment 0..3
  const int px = tx0i + (p & 15);
  const int py = ty0i + (p >> 4);
  const float fpx = (float)px, fpy = (float)py;

  const int L = (total + 3) >> 2;
  const int k0 = seg * L;
  const int k1 = min(k0 + L, total);

  float T = 1.f, accr = 0.f, accg = 0.f, accb = 0.f;

  for (int k = k0; k < k1; ++k) {
    const int n = (int)order[k];
    const float4 A = sgA[n];
    const float4 B = sgB[n];
    const float4 C = sgC[n];
    const unsigned int bx = __float_as_uint(C.y);
    const unsigned int by = __float_as_uint(C.z);
    const bool in = (px >= (int)(bx & 0xFFFFu)) & (px < (int)(bx >> 16)) &
                    (py >= (int)(by & 0xFFFFu)) & (py < (int)(by >> 16));
    const float dx = fpx - A.x;
    const float dy = fpy - A.y;
    const float m = A.z*dx*dx + A.w*dx*dy + B.x*dy*dy;
    const float g = __expf(-0.5f * m);
    float a = fminf(B.y * g, 0.99f);
    a = in ? a : 0.f;
    const float w = a * T;
    accr = fmaf(w, B.z, accr);
    accg = fmaf(w, B.w, accg);
    accb = fmaf(w, C.x, accb);
    T *= (1.f - a);
  }

  // butterfly merge of 4 ordered segments; all lanes end with full result
  {
    float pT = __shfl_xor(T, 1);
    float pr = __shfl_xor(accr, 1);
    float pg = __shfl_xor(accg, 1);
    float pb = __shfl_xor(accb, 1);
    if (seg & 1) { accr = pr + pT*accr; accg = pg + pT*accg; accb = pb + pT*accb; }
    else         { accr = accr + T*pr;  accg = accg + T*pg;  accb = accb + T*pb; }
    T *= pT;

    pT = __shfl_xor(T, 2);
    pr = __shfl_xor(accr, 2);
    pg = __shfl_xor(accg, 2);
    pb = __shfl_xor(accb, 2);
    if (seg & 2) { accr = pr + pT*accr; accg = pg + pT*accg; accb = pb + pT*accb; }
    else         { accr = accr + T*pr;  accg = accg + T*pg;  accb = accb + T*pb; }
  }

  // plane-parallel store: seg lane 0/1/2 writes R/G/B
  if (seg < 3) {
    const float val = (seg == 0) ? accr : (seg == 1) ? accg : accb;
    out[seg * (IMG_W*IMG_H) + py * IMG_W + px] = val;
  }
}

extern "C" void kernel_launch(void* const* d_in, const int* in_sizes, int n_in,
                              void* d_out, int out_size, void* d_ws, size_t ws_size,
                              hipStream_t stream) {
  const float* pos = (const float*)d_in[0];
  const float* scl = (const float*)d_in[1];
  const float* rot = (const float*)d_in[2];
  const float* col = (const float*)d_in[3];
  const float* opa = (const float*)d_in[4];
  const float* vm  = (const float*)d_in[5];

  const int tiles = (IMG_W / 16) * (IMG_H / 16);  // 256 tiles
  fused_render_kernel<<<tiles, 1024, 0, stream>>>(pos, scl, rot, col, opa, vm,
                                                  (float*)d_out);
}

// Round 7
// 11.789 us; speedup vs baseline: 1.0936x; 1.0936x over previous
//
#include <hip/hip_runtime.h>
#include <math.h>

#define NG     512
#define IMG_W  256
#define IMG_H  256
#define FXc    300.0f
#define FYc    300.0f
#define CXc    128.0f
#define CYc    128.0f
#define NEARc  0.01f
#define FARc   100.0f
#define MAXR   64.0f

// 64-byte param struct, indexed by original gaussian id.
struct GParam {
  float mx, my, ia, ibc;
  float idv, opac, cr, cg;
  float cb, x0, x1, y0;
  float y1, depth, pad1, pad2;
};

__device__ __forceinline__ unsigned int ordered_float(float f) {
  unsigned int u = __float_as_uint(f);
  return (u & 0x80000000u) ? ~u : (u | 0x80000000u);
}

__global__ __launch_bounds__(1024, 4) void fused_render_kernel(
    const float* __restrict__ pos, const float* __restrict__ scl,
    const float* __restrict__ rot, const float* __restrict__ col,
    const float* __restrict__ opa, const float* __restrict__ vm,
    float* __restrict__ out)
{
  __shared__ GParam sg[NG];               // 32 KB, by original index
  __shared__ unsigned long long keys[NG]; // 4 KB, compacted candidates
  __shared__ short order[NG];             // 1 KB, rank -> gaussian id
  __shared__ int wave_cnt[8];

  const int t = threadIdx.x;
  const int wid = t >> 6;      // 16 waves
  const int lane = t & 63;

  float V[12];
#pragma unroll
  for (int k = 0; k < 12; ++k) V[k] = vm[k];

  // ---- prep: 1 gaussian per thread (t < 512), replicated per block ----
  if (t < NG) {
    const int i = t;

    const float p0 = pos[i*3+0], p1 = pos[i*3+1], p2 = pos[i*3+2];
    const float pcx = V[0]*p0 + V[1]*p1 + V[2]*p2  + V[3];
    const float pcy = V[4]*p0 + V[5]*p1 + V[6]*p2  + V[7];
    const float pcz = V[8]*p0 + V[9]*p1 + V[10]*p2 + V[11];
    const float depth = -pcz;

    float qw = rot[i*4+0], qx = rot[i*4+1], qy = rot[i*4+2], qz = rot[i*4+3];
    const float qinv = 1.f / sqrtf(qw*qw + qx*qx + qy*qy + qz*qz);
    qw *= qinv; qx *= qinv; qy *= qinv; qz *= qinv;
    const float r00 = 1.f - 2.f*(qy*qy + qz*qz);
    const float r01 = 2.f*(qx*qy - qw*qz);
    const float r02 = 2.f*(qx*qz + qw*qy);
    const float r10 = 2.f*(qx*qy + qw*qz);
    const float r11 = 1.f - 2.f*(qx*qx + qz*qz);
    const float r12 = 2.f*(qy*qz - qw*qx);
    const float r20 = 2.f*(qx*qz - qw*qy);
    const float r21 = 2.f*(qy*qz + qw*qx);
    const float r22 = 1.f - 2.f*(qx*qx + qy*qy);

    const float s0 = scl[i*3+0], s1 = scl[i*3+1], s2 = scl[i*3+2];

    const float m00 = V[0]*r00 + V[1]*r10 + V[2]*r20;
    const float m01 = V[0]*r01 + V[1]*r11 + V[2]*r21;
    const float m02 = V[0]*r02 + V[1]*r12 + V[2]*r22;
    const float m10 = V[4]*r00 + V[5]*r10 + V[6]*r20;
    const float m11 = V[4]*r01 + V[5]*r11 + V[6]*r21;
    const float m12 = V[4]*r02 + V[5]*r12 + V[6]*r22;
    const float m20 = V[8]*r00 + V[9]*r10 + V[10]*r20;
    const float m21 = V[8]*r01 + V[9]*r11 + V[10]*r21;
    const float m22 = V[8]*r02 + V[9]*r12 + V[10]*r22;

    const float a0 = m00*s0, a1 = m01*s1, a2 = m02*s2;
    const float b0 = m10*s0, b1 = m11*s1, b2 = m12*s2;
    const float c0 = m20*s0, c1 = m21*s1, c2 = m22*s2;
    const float c00 = a0*a0 + a1*a1 + a2*a2;
    const float c01 = a0*b0 + a1*b1 + a2*b2;
    const float c02 = a0*c0 + a1*c1 + a2*c2;
    const float c11 = b0*b0 + b1*b1 + b2*b2;
    const float c12 = b0*c0 + b1*c1 + b2*c2;
    const float c22 = c0*c0 + c1*c1 + c2*c2;

    const float zp = pcz + 1e-8f;
    const float sgn = (zp > 0.f) ? 1.f : ((zp < 0.f) ? -1.f : 0.f);
    const float z_safe = fmaxf(fabsf(pcz), 0.01f) * sgn;
    const float rz2 = 1.f / (z_safe * z_safe);
    const float rnz = 1.f / (-z_safe);

    const float j00 = FXc * rnz;
    const float j02 = FXc * pcx * rz2;
    const float j11 = FYc * (-rnz);
    const float j12 = FYc * pcy * rz2;

    const float t00 = j00*c00 + j02*c02;
    const float t01 = j00*c01 + j02*c12;
    const float t02 = j00*c02 + j02*c22;
    const float t10 = j11*c01 + j12*c02;
    const float t11 = j11*c11 + j12*c12;
    const float t12 = j11*c12 + j12*c22;
    const float ca  = t00*j00 + t02*j02;
    const float cbv = t01*j11 + t02*j12;
    const float cc  = t10*j00 + t12*j02;
    const float cd  = t11*j11 + t12*j12;

    const float u = FXc * pcx * rnz + CXc;
    const float v = FYc * (-pcy) * rnz + CYc;

    const float trace = ca + cd;
    const float det = fmaxf(ca*cd - cbv*cc, 1e-6f);
    const float disc = fmaxf(trace*trace - 4.f*det, 0.f);
    const float lam = (trace + sqrtf(disc)) * 0.5f;
    const float radii = fminf(3.f * sqrtf(fmaxf(lam, 1e-6f)), MAXR);

    const bool visible = (depth > NEARc) && (depth < FARc) &&
                         (u + radii > 0.f) && (u - radii < (float)IMG_W) &&
                         (v + radii > 0.f) && (v - radii < (float)IMG_H);

    const float ra = ca + 1e-4f;
    const float rb = cbv;
    const float rc = cc;
    const float rd = cd + 1e-4f;
    const float inv_rdet = 1.f / (ra*rd - rb*rc);

    float x0 = fmaxf(0.f, truncf(u - radii));
    float x1 = fminf((float)IMG_W, truncf(u + radii) + 1.f);
    float y0 = fmaxf(0.f, truncf(v - radii));
    float y1 = fminf((float)IMG_H, truncf(v + radii) + 1.f);
    if (!visible) { x0 = 1e9f; x1 = -1e9f; y0 = 1e9f; y1 = -1e9f; }

    GParam g;
    g.mx = u; g.my = v; g.ia = rd * inv_rdet; g.ibc = -(rb + rc) * inv_rdet;
    g.idv = ra * inv_rdet; g.opac = opa[i]; g.cr = col[i*3+0]; g.cg = col[i*3+1];
    g.cb = col[i*3+2]; g.x0 = x0; g.x1 = x1; g.y0 = y0;
    g.y1 = y1; g.depth = depth; g.pad1 = 0.f; g.pad2 = 0.f;
    sg[i] = g;
  }
  __syncthreads();

  // ---- per-tile candidate compaction (waves 0..7 own 64 ids each) ----
  const int tileX = blockIdx.x % (IMG_W / 16);
  const int tileY = blockIdx.x / (IMG_W / 16);
  const float tx0 = (float)(tileX * 16), tx1 = tx0 + 16.f;
  const float ty0 = (float)(tileY * 16), ty1 = ty0 + 16.f;

  bool pred = false;
  unsigned long long mb = 0;
  if (wid < 8) {
    const int g = wid * 64 + lane;
    pred = (sg[g].x0 < tx1) & (sg[g].x1 > tx0) &
           (sg[g].y0 < ty1) & (sg[g].y1 > ty0);
    mb = __ballot(pred);
    if (lane == 0) wave_cnt[wid] = __popcll(mb);
  }
  __syncthreads();

  int off = 0, total = 0;
#pragma unroll
  for (int w = 0; w < 8; ++w) {
    const int c = wave_cnt[w];
    if (w < wid) off += c;
    total += c;
  }
  if (pred) {
    const int g = wid * 64 + lane;
    const int p = off + __popcll(mb & ((1ull << lane) - 1ull));
    keys[p] = ((unsigned long long)ordered_float(sg[g].depth) << 32)
            | (unsigned int)g;
  }
  __syncthreads();

  // ---- rank sort: unique keys, one key per thread, 1 barrier ----
  if (t < total) {
    const unsigned long long kj = keys[t];
    int rank = 0;
    int i = 0;
    for (; i + 4 <= total; i += 4) {
      rank += (keys[i]   < kj);
      rank += (keys[i+1] < kj);
      rank += (keys[i+2] < kj);
      rank += (keys[i+3] < kj);
    }
    for (; i < total; ++i) rank += (keys[i] < kj);
    order[rank] = (short)(kj & 0xFFFFull);
  }
  __syncthreads();

  // ---- segmented composite: 4 threads/pixel, contiguous quarters ----
  const int p = t >> 2;        // pixel 0..255
  const int seg = t & 3;       // segment 0..3
  const int lx = p & 15, ly = p >> 4;
  const int px = tileX * 16 + lx;
  const int py = tileY * 16 + ly;
  const float fpx = (float)px, fpy = (float)py;

  const int L = (total + 3) >> 2;           // segment length
  const int k0 = seg * L;
  const int k1 = min(k0 + L, total);

  float T = 1.f, accr = 0.f, accg = 0.f, accb = 0.f;

  for (int k = k0; k < k1; ++k) {
    const int n = (int)order[k];
    const float dx = fpx - sg[n].mx;
    const float dy = fpy - sg[n].my;
    const float m = sg[n].ia*dx*dx + sg[n].ibc*dx*dy + sg[n].idv*dy*dy;
    const float g = __expf(-0.5f * m);
    const bool in = (fpx >= sg[n].x0) & (fpx < sg[n].x1) &
                    (fpy >= sg[n].y0) & (fpy < sg[n].y1);
    float a = fminf(sg[n].opac * g, 0.99f);
    a = in ? a : 0.f;
    const float w = a * T;
    accr = fmaf(w, sg[n].cr, accr);
    accg = fmaf(w, sg[n].cg, accg);
    accb = fmaf(w, sg[n].cb, accb);
    T *= (1.f - a);
  }

  // combine 4 segments (lanes seg^1 then seg^2), order-aware:
  // lower-segment lane: acc + T*p_acc ; upper: p_acc + p_T*acc
  {
    float pT = __shfl_xor(T, 1);
    float pr = __shfl_xor(accr, 1);
    float pg = __shfl_xor(accg, 1);
    float pb = __shfl_xor(accb, 1);
    if (seg & 1) { accr = pr + pT*accr; accg = pg + pT*accg; accb = pb + pT*accb; }
    else         { accr = accr + T*pr;  accg = accg + T*pg;  accb = accb + T*pb; }
    T *= pT;

    pT = __shfl_xor(T, 2);
    pr = __shfl_xor(accr, 2);
    pg = __shfl_xor(accg, 2);
    pb = __shfl_xor(accb, 2);
    if (seg & 2) { accr = pr + pT*accr; accg = pg + pT*accg; accb = pb + pT*accb; }
    else         { accr = accr + T*pr;  accg = accg + T*pg;  accb = accb + T*pb; }
    T *= pT;
  }

  if (seg == 0) {
    const int pix = py * IMG_W + px;
    out[0*IMG_W*IMG_H + pix] = accr;
    out[1*IMG_W*IMG_H + pix] = accg;
    out[2*IMG_W*IMG_H + pix] = accb;
  }
}

extern "C" void kernel_launch(void* const* d_in, const int* in_sizes, int n_in,
                              void* d_out, int out_size, void* d_ws, size_t ws_size,
                              hipStream_t stream) {
  const float* pos = (const float*)d_in[0];
  const float* scl = (const float*)d_in[1];
  const float* rot = (const float*)d_in[2];
  const float* col = (const float*)d_in[3];
  const float* opa = (const float*)d_in[4];
  const float* vm  = (const float*)d_in[5];

  const int tiles = (IMG_W / 16) * (IMG_H / 16);  // 256 tiles
  fused_render_kernel<<<tiles, 1024, 0, stream>>>(pos, scl, rot, col, opa, vm,
                                                  (float*)d_out);
}